// Round 1
// baseline (1242.443 us; speedup 1.0000x reference)
//
#include <hip/hip_runtime.h>
#include <hip/hip_bf16.h>
#include <math.h>

#define CC 256
#define PP 4096            // H*W = 64*64
#define NEG_INF_V -100000000.0f

// -------------------- conv3x3 + bias + relu --------------------
// grid: (16 spatial tiles of 16x16, C/8=32 co-groups, B=2), block 256
__global__ __launch_bounds__(256) void conv3x3_relu_k(
    const float* __restrict__ in, const float* __restrict__ w,
    const float* __restrict__ bias, float* __restrict__ out) {
  __shared__ float s_in[18 * 18];
  __shared__ float s_w[9][8];
  const int t = threadIdx.x;
  const int tile = blockIdx.x;
  const int co0 = blockIdx.y * 8;
  const int b = blockIdx.z;
  const int y0 = (tile >> 2) * 16, x0 = (tile & 3) * 16;
  const int px = t & 15, py = t >> 4;
  float acc[8];
#pragma unroll
  for (int o = 0; o < 8; ++o) acc[o] = 0.f;
  const float* inb = in + (size_t)b * CC * PP;

  for (int ci = 0; ci < CC; ++ci) {
    // stage 18x18 halo tile
    for (int i = t; i < 324; i += 256) {
      int ly = i / 18, lx = i - ly * 18;
      int gy = y0 + ly - 1, gx = x0 + lx - 1;
      float v = 0.f;
      if ((unsigned)gy < 64u && (unsigned)gx < 64u)
        v = inb[(size_t)ci * PP + gy * 64 + gx];
      s_in[i] = v;
    }
    if (t < 72) {
      int o = t / 9, k = t - o * 9;
      s_w[k][o] = w[(((size_t)(co0 + o)) * CC + ci) * 9 + k];
    }
    __syncthreads();
#pragma unroll
    for (int ky = 0; ky < 3; ++ky) {
#pragma unroll
      for (int kx = 0; kx < 3; ++kx) {
        float v = s_in[(py + ky) * 18 + px + kx];
        const int k = ky * 3 + kx;
#pragma unroll
        for (int o = 0; o < 8; ++o) acc[o] = fmaf(v, s_w[k][o], acc[o]);
      }
    }
    __syncthreads();
  }
  const size_t obase = (size_t)b * CC * PP + (size_t)(y0 + py) * 64 + (x0 + px);
#pragma unroll
  for (int o = 0; o < 8; ++o) {
    float v = acc[o] + bias[co0 + o];
    out[obase + (size_t)(co0 + o) * PP] = v > 0.f ? v : 0.f;
  }
}

// -------------------- 1x1 conv = GEMM [CO x C] @ [C x P] --------------------
// grid: (P/64, ceil(CO/64), B), block 256; each thread 4co x 4p
__global__ __launch_bounds__(256) void conv1x1_k(
    const float* __restrict__ in, const float* __restrict__ w,
    const float* __restrict__ bias, float* __restrict__ out, int CO) {
  __shared__ __align__(16) float s_in[16][64];
  __shared__ float s_w[64][17];
  const int t = threadIdx.x;
  const int p0 = blockIdx.x * 64, co0 = blockIdx.y * 64, b = blockIdx.z;
  const int tq = t & 15, tp = t >> 4;
  float acc[4][4];
#pragma unroll
  for (int i = 0; i < 4; ++i)
#pragma unroll
    for (int j = 0; j < 4; ++j) acc[i][j] = 0.f;
  const float* inb = in + (size_t)b * CC * PP;
  const int lr = t >> 6, lcol = t & 63;
  const int wr = t >> 4, wc = t & 15;

  for (int c0 = 0; c0 < CC; c0 += 16) {
#pragma unroll
    for (int rr = 0; rr < 4; ++rr)
      s_in[lr + rr * 4][lcol] = inb[(size_t)(c0 + lr + rr * 4) * PP + p0 + lcol];
#pragma unroll
    for (int rr = 0; rr < 4; ++rr) {
      int co = co0 + wr + rr * 16;
      s_w[wr + rr * 16][wc] = (co < CO) ? w[(size_t)co * CC + c0 + wc] : 0.f;
    }
    __syncthreads();
#pragma unroll
    for (int kk = 0; kk < 16; ++kk) {
      float4 bv4 = *(const float4*)&s_in[kk][tq * 4];
      float bvv[4] = {bv4.x, bv4.y, bv4.z, bv4.w};
      float avv[4];
#pragma unroll
      for (int i = 0; i < 4; ++i) avv[i] = s_w[tp * 4 + i][kk];
#pragma unroll
      for (int i = 0; i < 4; ++i)
#pragma unroll
        for (int j = 0; j < 4; ++j) acc[i][j] = fmaf(avv[i], bvv[j], acc[i][j]);
    }
    __syncthreads();
  }
#pragma unroll
  for (int i = 0; i < 4; ++i) {
    int co = co0 + tp * 4 + i;
    if (co < CO) {
      float bi = bias[co];
#pragma unroll
      for (int j = 0; j < 4; ++j)
        out[((size_t)b * CO + co) * PP + p0 + tq * 4 + j] = acc[i][j] + bi;
    }
  }
}

// -------------------- logits GEMM + mask + fused dice partials --------------------
// grid: (64 q-blocks, 64 p-blocks, B), block 256; each thread 4p x 4q
__global__ __launch_bounds__(256) void logits_loss_k(
    const float* __restrict__ ker, const float* __restrict__ ff,
    const float* __restrict__ masks, const int* __restrict__ layouts,
    float* __restrict__ out, float* __restrict__ partial) {
  __shared__ __align__(16) float s_a[16][64];
  __shared__ __align__(16) float s_b[16][64];
  __shared__ float s_red[64][16];
  const int t = threadIdx.x;
  const int tq = t & 15, tp = t >> 4;
  const int q0 = blockIdx.x * 64, p0 = blockIdx.y * 64, b = blockIdx.z;
  const float* kerb = ker + (size_t)b * 257 * PP;
  const float* fb = ff + (size_t)b * CC * PP;
  float acc[4][4];
#pragma unroll
  for (int i = 0; i < 4; ++i)
#pragma unroll
    for (int j = 0; j < 4; ++j) acc[i][j] = 0.f;
  const int lr = t >> 6, lcol = t & 63;

  for (int c0 = 0; c0 < CC; c0 += 16) {
#pragma unroll
    for (int rr = 0; rr < 4; ++rr) {
      s_a[lr + rr * 4][lcol] = kerb[(size_t)(c0 + lr + rr * 4) * PP + p0 + lcol];
      s_b[lr + rr * 4][lcol] = fb[(size_t)(c0 + lr + rr * 4) * PP + q0 + lcol];
    }
    __syncthreads();
#pragma unroll
    for (int kk = 0; kk < 16; ++kk) {
      float4 av4 = *(const float4*)&s_a[kk][tp * 4];
      float4 bv4 = *(const float4*)&s_b[kk][tq * 4];
      float avv[4] = {av4.x, av4.y, av4.z, av4.w};
      float bvv[4] = {bv4.x, bv4.y, bv4.z, bv4.w};
#pragma unroll
      for (int i = 0; i < 4; ++i)
#pragma unroll
        for (int j = 0; j < 4; ++j) acc[i][j] = fmaf(avv[i], bvv[j], acc[i][j]);
    }
    __syncthreads();
  }

  // epilogue: +kb, mask, write logits, fused dice partial over q
  float kb[4];
  int layp[4];
#pragma unroll
  for (int i = 0; i < 4; ++i) {
    kb[i] = kerb[(size_t)256 * PP + p0 + tp * 4 + i];
    layp[i] = layouts[b * PP + p0 + tp * 4 + i];
  }
  float mq[4];
  int layq[4];
#pragma unroll
  for (int j = 0; j < 4; ++j) {
    mq[j] = masks[b * PP + q0 + tq * 4 + j];
    layq[j] = layouts[b * PP + q0 + tq * 4 + j];
  }
  float sl[4] = {0.f, 0.f, 0.f, 0.f};
#pragma unroll
  for (int i = 0; i < 4; ++i) {
    float4 ov;
    float* po = (float*)&ov;
#pragma unroll
    for (int j = 0; j < 4; ++j) {
      float x = acc[i][j] + kb[i];
      float lg = (mq[j] > 0.f) ? x : NEG_INF_V;
      po[j] = lg;
      float pz = 1.f / (1.f + expf(-lg));   // lg=NEG_INF -> pz=0, masked out anyway
      float l = (layp[i] == layq[j]) ? 1.f : 0.f;
      float d = 2.f * pz * l / (pz * pz + l * l + 0.002f);
      sl[i] += (1.f - d) * mq[j];
    }
    *(float4*)&out[(size_t)b * PP * PP + (size_t)(p0 + tp * 4 + i) * PP + q0 + tq * 4] = ov;
  }
  __syncthreads();
#pragma unroll
  for (int i = 0; i < 4; ++i) s_red[tp * 4 + i][tq] = sl[i];
  __syncthreads();
  if (t < 64) {
    float s = 0.f;
#pragma unroll
    for (int k = 0; k < 16; ++k) s += s_red[t][k];
    partial[((size_t)b * PP + p0 + t) * 64 + blockIdx.x] = s;
  }
}

// -------------------- final loss reduction (1 block) --------------------
__global__ __launch_bounds__(256) void loss_k(
    const float* __restrict__ partial, const float* __restrict__ masks,
    float* __restrict__ out_loss) {
  __shared__ double sd[256];
  const int t = threadIdx.x;
  double loss = 0.0;
  for (int b = 0; b < 2; ++b) {
    double g = 0.0;
    for (int q = t; q < PP; q += 256) g += (double)masks[b * PP + q];
    sd[t] = g;
    __syncthreads();
    for (int s = 128; s > 0; s >>= 1) {
      if (t < s) sd[t] += sd[t + s];
      __syncthreads();
    }
    double gtot = sd[0];
    __syncthreads();
    double num = 0.0;
    for (int p = t; p < PP; p += 256) {
      float mp = masks[b * PP + p];
      if (mp > 0.f) {
        double s2 = 0.0;
        const float* pp = partial + ((size_t)b * PP + p) * 64;
        for (int k = 0; k < 64; ++k) s2 += (double)pp[k];
        num += s2 * (double)mp;
      }
    }
    sd[t] = num;
    __syncthreads();
    for (int s = 128; s > 0; s >>= 1) {
      if (t < s) sd[t] += sd[t + s];
      __syncthreads();
    }
    if (t == 0) loss += sd[0] / (gtot * gtot + (double)1e-5);
    __syncthreads();
  }
  if (t == 0) out_loss[0] = (float)(loss * 0.5);
}

extern "C" void kernel_launch(void* const* d_in, const int* in_sizes, int n_in,
                              void* d_out, int out_size, void* d_ws, size_t ws_size,
                              hipStream_t stream) {
  const float* feats   = (const float*)d_in[0];
  const float* masks   = (const float*)d_in[1];
  const int*   layouts = (const int*)d_in[2];
  const float* w_pre0  = (const float*)d_in[3];
  const float* b_pre0  = (const float*)d_in[4];
  const float* w_pre1  = (const float*)d_in[5];
  const float* b_pre1  = (const float*)d_in[6];
  const float* w_kernel = (const float*)d_in[7];
  const float* b_kernel = (const float*)d_in[8];
  const float* w_feats  = (const float*)d_in[9];
  const float* b_feats  = (const float*)d_in[10];

  float* ws = (float*)d_ws;
  float* h1 = ws;                       // 2*256*4096 = 2097152 floats
  float* h2 = ws + 2097152;             // 2097152
  float* ker = ws + 2 * 2097152;        // 2*257*4096 = 2105344
  float* partial = ws + 2 * 2097152 + 2105344;  // 2*4096*64 = 524288
  float* ff = h1;                       // reuse h1 slot after conv2 consumes it

  float* out = (float*)d_out;

  conv3x3_relu_k<<<dim3(16, 32, 2), 256, 0, stream>>>(feats, w_pre0, b_pre0, h1);
  conv3x3_relu_k<<<dim3(16, 32, 2), 256, 0, stream>>>(h1, w_pre1, b_pre1, h2);
  conv1x1_k<<<dim3(64, 5, 2), 256, 0, stream>>>(h2, w_kernel, b_kernel, ker, 257);
  conv1x1_k<<<dim3(64, 4, 2), 256, 0, stream>>>(feats, w_feats, b_feats, ff, 256);
  logits_loss_k<<<dim3(64, 64, 2), 256, 0, stream>>>(ker, ff, masks, layouts, out, partial);
  loss_k<<<1, 256, 0, stream>>>(partial, masks, out + (size_t)2 * PP * PP);
}

// Round 2
// 303.997 us; speedup vs baseline: 4.0870x; 4.0870x over previous
//
#include <hip/hip_runtime.h>
#include <hip/hip_bf16.h>
#include <math.h>

typedef __attribute__((ext_vector_type(8))) short bf16x8;
typedef __attribute__((ext_vector_type(4))) float f32x4;
typedef __hip_bfloat16 bf16_t;

#define NEG_INF_V -100000000.0f

__device__ __forceinline__ void gload16(const void* g, void* l) {
  __builtin_amdgcn_global_load_lds(
      (const __attribute__((address_space(1))) unsigned int*)g,
      (__attribute__((address_space(3))) unsigned int*)l, 16, 0, 0);
}

// ---------- feats NCHW fp32 -> x_pad [B][66][66][256] bf16 (interior) ----------
__global__ __launch_bounds__(256) void pad_cast_k(
    const float* __restrict__ feats, bf16_t* __restrict__ x_pad) {
  __shared__ float s[64][65];
  const int t = threadIdx.x;
  const int y = blockIdx.x, c0 = blockIdx.y * 64, b = blockIdx.z;
  const float* fb = feats + ((size_t)b * 256 + c0) * 4096 + y * 64;
  for (int i = t; i < 64 * 64; i += 256) {
    int ci = i >> 6, x = i & 63;
    s[ci][x] = fb[(size_t)ci * 4096 + x];
  }
  __syncthreads();
  bf16_t* xp = x_pad + (size_t)b * (66 * 66 * 256) + ((size_t)(y + 1) * 66 + 1) * 256 + c0;
  for (int i = t; i < 64 * 64; i += 256) {
    int x = i >> 6, ci = i & 63;
    xp[(size_t)x * 256 + ci] = __float2bfloat16(s[ci][x]);
  }
}

// ---------- w_pre [256][256][3][3] fp32 -> [co][9][256] bf16 ----------
__global__ __launch_bounds__(256) void castw3_k(
    const float* __restrict__ w0, const float* __restrict__ w1,
    bf16_t* __restrict__ o0, bf16_t* __restrict__ o1) {
  const int co = blockIdx.x, t = threadIdx.x;
  const float* ws = blockIdx.y ? w1 : w0;
  bf16_t* wd = blockIdx.y ? o1 : o0;
#pragma unroll
  for (int k = 0; k < 9; ++k)
    wd[(size_t)co * 2304 + k * 256 + t] = __float2bfloat16(ws[((size_t)co * 256 + t) * 9 + k]);
}

// ---------- 1x1 weights -> bf16 ----------
__global__ __launch_bounds__(256) void castw1_k(
    const float* __restrict__ wk, const float* __restrict__ wf,
    bf16_t* __restrict__ ok, bf16_t* __restrict__ of) {
  int i = blockIdx.x * 256 + threadIdx.x;
  if (i < 257 * 256) ok[i] = __float2bfloat16(wk[i]);
  else { int j = i - 257 * 256; if (j < 256 * 256) of[j] = __float2bfloat16(wf[j]); }
}

// ---------- conv3x3 (+bias+relu) as implicit GEMM, bf16 MFMA ----------
// grid (64 y-rows, 2 co-tiles, B), 256 thr = 4 waves (2x2), tile 64x128, K=9*256
__global__ __launch_bounds__(256) void conv3x3_mfma_k(
    const bf16_t* __restrict__ xpad, const bf16_t* __restrict__ wr,
    const float* __restrict__ bias, bf16_t* __restrict__ out,
    int out_row_stride, int out_base, long out_bstride) {
  __shared__ __align__(16) short ldsA[64 * 32];
  __shared__ __align__(16) short ldsB[128 * 32];
  const int t = threadIdx.x, w = t >> 6, lane = t & 63;
  const int y = blockIdx.x, co0 = blockIdx.y * 128, b = blockIdx.z;
  const bf16_t* xb = xpad + (size_t)b * (66 * 66 * 256);
  const int wm = w >> 1, wn = w & 1;
  f32x4 acc[2][4] = {};
  const int spix = w * 16 + (lane >> 2);
  const int scio = (lane & 3) * 8;
  const int sbco = w * 32 + (lane >> 2);
  const int aoff = (wm * 32 + (lane & 15)) * 32 + (lane >> 4) * 8;
  const int boff = (wn * 64 + (lane & 15)) * 32 + (lane >> 4) * 8;
  short* ldsAw = &ldsA[w * 512];
  short* ldsBw0 = &ldsB[(w * 32) * 32];
  short* ldsBw1 = &ldsB[(w * 32 + 16) * 32];

  for (int ks = 0; ks < 72; ++ks) {
    const int kpos = ks >> 3, cik = (ks & 7) * 32;
    const int ky = (kpos * 11) >> 5, kx = kpos - 3 * ky;
    gload16(xb + ((size_t)(y + ky) * 66 + spix + kx) * 256 + cik + scio, ldsAw);
    const bf16_t* gb = wr + (size_t)(co0 + sbco) * 2304 + kpos * 256 + cik + scio;
    gload16(gb, ldsBw0);
    gload16(gb + 16 * 2304, ldsBw1);
    __syncthreads();
    bf16x8 af0 = *(const bf16x8*)&ldsA[aoff];
    bf16x8 af1 = *(const bf16x8*)&ldsA[aoff + 512];
#pragma unroll
    for (int n = 0; n < 4; ++n) {
      bf16x8 bf = *(const bf16x8*)&ldsB[boff + n * 512];
      acc[0][n] = __builtin_amdgcn_mfma_f32_16x16x32_bf16(af0, bf, acc[0][n], 0, 0, 0);
      acc[1][n] = __builtin_amdgcn_mfma_f32_16x16x32_bf16(af1, bf, acc[1][n], 0, 0, 0);
    }
    __syncthreads();
  }
  bf16_t* ob = out + (size_t)b * out_bstride;
  float bv[4];
#pragma unroll
  for (int n = 0; n < 4; ++n) bv[n] = bias[co0 + wn * 64 + n * 16 + (lane & 15)];
#pragma unroll
  for (int m = 0; m < 2; ++m) {
#pragma unroll
    for (int r = 0; r < 4; ++r) {
      int x = wm * 32 + m * 16 + (lane >> 4) * 4 + r;
      size_t ra = (size_t)out_base + (size_t)y * out_row_stride + (size_t)x * 256 + co0 + wn * 64 + (lane & 15);
#pragma unroll
      for (int n = 0; n < 4; ++n) {
        float v = acc[m][n][r] + bv[n];
        ob[ra + n * 16] = __float2bfloat16(fmaxf(v, 0.f));
      }
    }
  }
}

// ---------- 1x1 conv GEMM: A [4096x256] NHWC act, B [CO][256] weights ----------
// KER: CO=257 -> kw_t [p][256] bf16 + kb [p] f32 ; else CO=256 -> ff_t [q][256]
template <bool KER>
__global__ __launch_bounds__(256) void conv1x1_mfma_k(
    const bf16_t* __restrict__ in, const bf16_t* __restrict__ wt,
    const float* __restrict__ bias, bf16_t* __restrict__ outw,
    float* __restrict__ outkb, int A0, int AS, long in_bstride, int comax) {
  __shared__ __align__(16) short ldsA[64 * 32];
  __shared__ __align__(16) short ldsB[128 * 32];
  const int t = threadIdx.x, w = t >> 6, lane = t & 63;
  const int y = blockIdx.x, co0 = blockIdx.y * 128, b = blockIdx.z;
  const bf16_t* inb = in + (size_t)b * in_bstride;
  const int wm = w >> 1, wn = w & 1;
  f32x4 acc[2][4] = {};
  const int spix = w * 16 + (lane >> 2);
  const int scio = (lane & 3) * 8;
  const int sbco = co0 + w * 32 + (lane >> 2);
  const int aoff = (wm * 32 + (lane & 15)) * 32 + (lane >> 4) * 8;
  const int boff = (wn * 64 + (lane & 15)) * 32 + (lane >> 4) * 8;
  short* ldsAw = &ldsA[w * 512];
  short* ldsBw0 = &ldsB[(w * 32) * 32];
  short* ldsBw1 = &ldsB[(w * 32 + 16) * 32];

  for (int ks = 0; ks < 8; ++ks) {
    const int cik = ks * 32;
    gload16(inb + (size_t)A0 + (size_t)y * AS + (size_t)spix * 256 + cik + scio, ldsAw);
    int c0r = min(sbco, comax - 1), c1r = min(sbco + 16, comax - 1);
    gload16(wt + (size_t)c0r * 256 + cik + scio, ldsBw0);
    gload16(wt + (size_t)c1r * 256 + cik + scio, ldsBw1);
    __syncthreads();
    bf16x8 af0 = *(const bf16x8*)&ldsA[aoff];
    bf16x8 af1 = *(const bf16x8*)&ldsA[aoff + 512];
#pragma unroll
    for (int n = 0; n < 4; ++n) {
      bf16x8 bf = *(const bf16x8*)&ldsB[boff + n * 512];
      acc[0][n] = __builtin_amdgcn_mfma_f32_16x16x32_bf16(af0, bf, acc[0][n], 0, 0, 0);
      acc[1][n] = __builtin_amdgcn_mfma_f32_16x16x32_bf16(af1, bf, acc[1][n], 0, 0, 0);
    }
    __syncthreads();
  }
#pragma unroll
  for (int m = 0; m < 2; ++m) {
#pragma unroll
    for (int r = 0; r < 4; ++r) {
      int x = wm * 32 + m * 16 + (lane >> 4) * 4 + r;
      int prow = y * 64 + x;
#pragma unroll
      for (int n = 0; n < 4; ++n) {
        int co = co0 + wn * 64 + n * 16 + (lane & 15);
        float v = acc[m][n][r] + bias[min(co, comax - 1)];
        if (KER) {
          if (co < 256) outw[((size_t)b * 4096 + prow) * 256 + co] = __float2bfloat16(v);
          else if (co == 256) outkb[(size_t)b * 4096 + prow] = v;
        } else {
          outw[((size_t)b * 4096 + prow) * 256 + co] = __float2bfloat16(v);
        }
      }
    }
  }
}

// ---------- logits GEMM + mask + write + fused dice partials ----------
// grid (64 p-tiles, 32 q-tiles, B); tile 64(p) x 128(q), K=256
__global__ __launch_bounds__(256) void logits_mfma_k(
    const bf16_t* __restrict__ kwt, const float* __restrict__ kb,
    const bf16_t* __restrict__ fft, const float* __restrict__ masks,
    const int* __restrict__ layouts, float* __restrict__ out,
    float* __restrict__ partial) {
  __shared__ __align__(16) short ldsA[64 * 32];
  __shared__ __align__(16) short ldsB[128 * 32];
  const int t = threadIdx.x, w = t >> 6, lane = t & 63;
  const int p0 = blockIdx.x * 64, q0 = blockIdx.y * 128, b = blockIdx.z;
  const bf16_t* ab = kwt + (size_t)b * (4096 * 256);
  const bf16_t* bb = fft + (size_t)b * (4096 * 256);
  const int wm = w >> 1, wn = w & 1;
  f32x4 acc[2][4] = {};
  const int spix = w * 16 + (lane >> 2);
  const int scio = (lane & 3) * 8;
  const int sbq = w * 32 + (lane >> 2);
  const int aoff = (wm * 32 + (lane & 15)) * 32 + (lane >> 4) * 8;
  const int boff = (wn * 64 + (lane & 15)) * 32 + (lane >> 4) * 8;
  short* ldsAw = &ldsA[w * 512];
  short* ldsBw0 = &ldsB[(w * 32) * 32];
  short* ldsBw1 = &ldsB[(w * 32 + 16) * 32];

  for (int ks = 0; ks < 8; ++ks) {
    const int cik = ks * 32;
    gload16(ab + (size_t)(p0 + spix) * 256 + cik + scio, ldsAw);
    gload16(bb + (size_t)(q0 + sbq) * 256 + cik + scio, ldsBw0);
    gload16(bb + (size_t)(q0 + sbq + 16) * 256 + cik + scio, ldsBw1);
    __syncthreads();
    bf16x8 af0 = *(const bf16x8*)&ldsA[aoff];
    bf16x8 af1 = *(const bf16x8*)&ldsA[aoff + 512];
#pragma unroll
    for (int n = 0; n < 4; ++n) {
      bf16x8 bf = *(const bf16x8*)&ldsB[boff + n * 512];
      acc[0][n] = __builtin_amdgcn_mfma_f32_16x16x32_bf16(af0, bf, acc[0][n], 0, 0, 0);
      acc[1][n] = __builtin_amdgcn_mfma_f32_16x16x32_bf16(af1, bf, acc[1][n], 0, 0, 0);
    }
    __syncthreads();
  }

  float mq[4];
  int layq[4];
#pragma unroll
  for (int n = 0; n < 4; ++n) {
    int q = q0 + wn * 64 + n * 16 + (lane & 15);
    mq[n] = masks[b * 4096 + q];
    layq[n] = layouts[b * 4096 + q];
  }
  float sl[8];
#pragma unroll
  for (int i = 0; i < 8; ++i) sl[i] = 0.f;
  float* outb = out + (size_t)b * 4096 * 4096;
#pragma unroll
  for (int m = 0; m < 2; ++m) {
#pragma unroll
    for (int r = 0; r < 4; ++r) {
      int p = p0 + wm * 32 + m * 16 + (lane >> 4) * 4 + r;
      float kbv = kb[b * 4096 + p];
      int layp = layouts[b * 4096 + p];
      float s = 0.f;
      size_t ra = (size_t)p * 4096 + q0 + wn * 64 + (lane & 15);
#pragma unroll
      for (int n = 0; n < 4; ++n) {
        float lg = (mq[n] > 0.f) ? (acc[m][n][r] + kbv) : NEG_INF_V;
        outb[ra + n * 16] = lg;
        float pz = 1.f / (1.f + __expf(-lg));
        float lab = (layp == layq[n]) ? 1.f : 0.f;
        float d = 2.f * pz * lab / (pz * pz + lab + 0.002f);
        s += (1.f - d) * mq[n];
      }
      sl[m * 4 + r] = s;
    }
  }
#pragma unroll
  for (int i = 0; i < 8; ++i) {
    float v = sl[i];
    v += __shfl_xor(v, 1); v += __shfl_xor(v, 2);
    v += __shfl_xor(v, 4); v += __shfl_xor(v, 8);
    sl[i] = v;
  }
  if ((lane & 15) == 0) {
    int qt = blockIdx.y * 2 + wn;
#pragma unroll
    for (int m = 0; m < 2; ++m)
#pragma unroll
      for (int r = 0; r < 4; ++r) {
        int p = p0 + wm * 32 + m * 16 + (lane >> 4) * 4 + r;
        partial[((size_t)b * 4096 + p) * 64 + qt] = sl[m * 4 + r];
      }
  }
}

// ---------- loss stage 1: per-p rowsum * mp, atomic accumulate ----------
__global__ __launch_bounds__(256) void rowsum_k(
    const float* __restrict__ partial, const float* __restrict__ masks,
    float* __restrict__ accum) {
  const int t = threadIdx.x, w = t >> 6, lane = t & 63;
  const int idx = blockIdx.x * 256 + t;
  const int b = idx >> 12;
  const float* pp = partial + (size_t)idx * 64;
  float s = 0.f;
#pragma unroll
  for (int k = 0; k < 64; ++k) s += pp[k];
  float mp = masks[idx];
  float num = s * mp;
#pragma unroll
  for (int off = 32; off; off >>= 1) {
    num += __shfl_down(num, off);
    mp += __shfl_down(mp, off);
  }
  __shared__ float sn[4], sm[4];
  if (lane == 0) { sn[w] = num; sm[w] = mp; }
  __syncthreads();
  if (t == 0) {
    atomicAdd(&accum[b * 2], sn[0] + sn[1] + sn[2] + sn[3]);
    atomicAdd(&accum[b * 2 + 1], sm[0] + sm[1] + sm[2] + sm[3]);
  }
}

__global__ void loss_final_k(const float* __restrict__ accum, float* __restrict__ out_loss) {
  if (threadIdx.x == 0) {
    float l0 = accum[0] / (accum[1] * accum[1] + 1e-5f);
    float l1 = accum[2] / (accum[3] * accum[3] + 1e-5f);
    out_loss[0] = 0.5f * (l0 + l1);
  }
}

extern "C" void kernel_launch(void* const* d_in, const int* in_sizes, int n_in,
                              void* d_out, int out_size, void* d_ws, size_t ws_size,
                              hipStream_t stream) {
  const float* feats = (const float*)d_in[0];
  const float* masks = (const float*)d_in[1];
  const int* layouts = (const int*)d_in[2];
  const float* w_pre0 = (const float*)d_in[3];
  const float* b_pre0 = (const float*)d_in[4];
  const float* w_pre1 = (const float*)d_in[5];
  const float* b_pre1 = (const float*)d_in[6];
  const float* w_kernel = (const float*)d_in[7];
  const float* b_kernel = (const float*)d_in[8];
  const float* w_feats = (const float*)d_in[9];
  const float* b_feats = (const float*)d_in[10];

  bf16_t* x_pad = (bf16_t*)d_ws;                 // 2*1115136
  bf16_t* h1p = x_pad + 2 * 1115136;             // 2*1115136
  bf16_t* h2 = h1p + 2 * 1115136;                // 2*1048576
  bf16_t* w0r = h2 + 2 * 1048576;                // 589824
  bf16_t* w1r = w0r + 589824;                    // 589824
  bf16_t* wkb = w1r + 589824;                    // 65792
  bf16_t* wfb = wkb + 65792;                     // 65536
  bf16_t* kwt = wfb + 65536;                     // 2*1048576
  bf16_t* fft = kwt + 2 * 1048576;               // 2*1048576
  float* kb = (float*)(fft + 2 * 1048576);       // 8192
  float* partial = kb + 8192;                    // 524288
  float* accum = partial + 524288;               // 4
  float* out = (float*)d_out;

  // zero padded borders (covers x_pad + h1p contiguously) and accum
  hipMemsetAsync(x_pad, 0, (size_t)4 * 1115136 * sizeof(bf16_t), stream);
  hipMemsetAsync(accum, 0, 4 * sizeof(float), stream);

  pad_cast_k<<<dim3(64, 4, 2), 256, 0, stream>>>(feats, x_pad);
  castw3_k<<<dim3(256, 2), 256, 0, stream>>>(w_pre0, w_pre1, w0r, w1r);
  castw1_k<<<dim3(514), 256, 0, stream>>>(w_kernel, w_feats, wkb, wfb);

  conv3x3_mfma_k<<<dim3(64, 2, 2), 256, 0, stream>>>(
      x_pad, w0r, b_pre0, h1p, 66 * 256, 67 * 256, 1115136L);
  conv3x3_mfma_k<<<dim3(64, 2, 2), 256, 0, stream>>>(
      h1p, w1r, b_pre1, h2, 64 * 256, 0, 1048576L);

  conv1x1_mfma_k<true><<<dim3(64, 3, 2), 256, 0, stream>>>(
      h2, wkb, b_kernel, kwt, kb, 0, 16384, 1048576L, 257);
  conv1x1_mfma_k<false><<<dim3(64, 2, 2), 256, 0, stream>>>(
      x_pad, wfb, b_feats, fft, nullptr, 67 * 256, 66 * 256, 1115136L, 256);

  logits_mfma_k<<<dim3(64, 32, 2), 256, 0, stream>>>(
      kwt, kb, fft, masks, layouts, out, partial);

  rowsum_k<<<dim3(32), 256, 0, stream>>>(partial, masks, accum);
  loss_final_k<<<1, 64, 0, stream>>>(accum, out + (size_t)2 * 4096 * 4096);
}

// Round 4
// 283.368 us; speedup vs baseline: 4.3846x; 1.0728x over previous
//
#include <hip/hip_runtime.h>
#include <hip/hip_bf16.h>
#include <math.h>

typedef __attribute__((ext_vector_type(8))) short bf16x8;
typedef __attribute__((ext_vector_type(4))) float f32x4;
typedef __hip_bfloat16 bf16_t;

#define NEG_INF_V -100000000.0f

__device__ __forceinline__ void gload16(const void* g, void* l) {
  __builtin_amdgcn_global_load_lds(
      (const __attribute__((address_space(1))) unsigned int*)g,
      (__attribute__((address_space(3))) unsigned int*)l, 16, 0, 0);
}

// swizzled ds_read of one bf16x8 fragment: row r (8 16B-units per row),
// logical 16B-slot c (0..7). Physical slot = c ^ (r&7)  (T2 / rule #21).
__device__ __forceinline__ bf16x8 swzread(const short* base, int r, int c) {
  return *(const bf16x8*)(base + ((r * 8 + (c ^ (r & 7))) << 3));
}

// ---------- feats NCHW fp32 -> x_pad [B][66][66][256] bf16 (interior) ----------
__global__ __launch_bounds__(256) void pad_cast_k(
    const float* __restrict__ feats, bf16_t* __restrict__ x_pad) {
  __shared__ float s[64][65];
  const int t = threadIdx.x;
  const int y = blockIdx.x, c0 = blockIdx.y * 64, b = blockIdx.z;
  const float* fb = feats + ((size_t)b * 256 + c0) * 4096 + y * 64;
  for (int i = t; i < 64 * 64; i += 256) {
    int ci = i >> 6, x = i & 63;
    s[ci][x] = fb[(size_t)ci * 4096 + x];
  }
  __syncthreads();
  bf16_t* xp = x_pad + (size_t)b * (66 * 66 * 256) + ((size_t)(y + 1) * 66 + 1) * 256 + c0;
  for (int i = t; i < 64 * 64; i += 256) {
    int x = i >> 6, ci = i & 63;
    xp[(size_t)x * 256 + ci] = __float2bfloat16(s[ci][x]);
  }
}

// ---------- w_pre [256][256][3][3] fp32 -> [co][9][256] bf16 ----------
__global__ __launch_bounds__(256) void castw3_k(
    const float* __restrict__ w0, const float* __restrict__ w1,
    bf16_t* __restrict__ o0, bf16_t* __restrict__ o1) {
  const int co = blockIdx.x, t = threadIdx.x;
  const float* ws = blockIdx.y ? w1 : w0;
  bf16_t* wd = blockIdx.y ? o1 : o0;
#pragma unroll
  for (int k = 0; k < 9; ++k)
    wd[(size_t)co * 2304 + k * 256 + t] = __float2bfloat16(ws[((size_t)co * 256 + t) * 9 + k]);
}

// ---------- 1x1 weights -> bf16 ----------
__global__ __launch_bounds__(256) void castw1_k(
    const float* __restrict__ wk, const float* __restrict__ wf,
    bf16_t* __restrict__ ok, bf16_t* __restrict__ of) {
  int i = blockIdx.x * 256 + threadIdx.x;
  if (i < 257 * 256) ok[i] = __float2bfloat16(wk[i]);
  else { int j = i - 257 * 256; if (j < 256 * 256) of[j] = __float2bfloat16(wf[j]); }
}

// ---------- conv3x3 (+bias+relu) implicit GEMM, 2-phase dbuf, BK=64 ----------
// grid (64 y-rows, 4 co-tiles of 64, B); tile 64px x 64co; K = 9*256, 36 steps
__global__ __launch_bounds__(256) void conv3x3_mfma_k(
    const bf16_t* __restrict__ xpad, const bf16_t* __restrict__ wr,
    const float* __restrict__ bias, bf16_t* __restrict__ out,
    int out_row_stride, int out_base, long out_bstride) {
  __shared__ __align__(16) short ldsA[2][4096];
  __shared__ __align__(16) short ldsB[2][4096];
  const int t = threadIdx.x, w = t >> 6, lane = t & 63;
  const int y = blockIdx.x, co0 = blockIdx.y * 64, b = blockIdx.z;
  const bf16_t* xb = xpad + (size_t)b * (66 * 66 * 256);
  const int wm = w >> 1, wn = w & 1;
  f32x4 acc[2][2] = {};

  int ar[2], ac[2];
#pragma unroll
  for (int p = 0; p < 2; ++p) {
    int u = (p * 4 + w) * 64 + lane;
    ar[p] = u >> 3;
    ac[p] = ((u & 7) ^ ((u >> 3) & 7)) * 8;   // inverse-swizzled source slot
  }
  const int fr = lane & 15, fc = lane >> 4;

  auto stage = [&](int ks, int buf) {
    int kpos = ks >> 2, cik = (ks & 3) * 64;
    int ky = (kpos * 11) >> 5, kx = kpos - 3 * ky;
#pragma unroll
    for (int p = 0; p < 2; ++p) {
      gload16(xb + ((size_t)(y + ky) * 66 + (ar[p] + kx)) * 256 + cik + ac[p],
              &ldsA[buf][(p * 4 + w) * 512]);
      gload16(wr + (size_t)(co0 + ar[p]) * 2304 + kpos * 256 + cik + ac[p],
              &ldsB[buf][(p * 4 + w) * 512]);
    }
  };
  auto compute = [&](int buf) {
#pragma unroll
    for (int kk = 0; kk < 2; ++kk) {
      bf16x8 af[2], bfr[2];
#pragma unroll
      for (int m = 0; m < 2; ++m) af[m] = swzread(ldsA[buf], wm * 32 + m * 16 + fr, kk * 4 + fc);
#pragma unroll
      for (int n = 0; n < 2; ++n) bfr[n] = swzread(ldsB[buf], wn * 32 + n * 16 + fr, kk * 4 + fc);
#pragma unroll
      for (int m = 0; m < 2; ++m)
#pragma unroll
        for (int n = 0; n < 2; ++n)
          acc[m][n] = __builtin_amdgcn_mfma_f32_16x16x32_bf16(af[m], bfr[n], acc[m][n], 0, 0, 0);
    }
  };

  stage(0, 0);
  __syncthreads();
  for (int ks = 0; ks < 35; ++ks) {
    stage(ks + 1, (ks + 1) & 1);
    compute(ks & 1);
    __syncthreads();
  }
  compute(1);

  bf16_t* ob = out + (size_t)b * out_bstride;
  float bv[2];
#pragma unroll
  for (int n = 0; n < 2; ++n) bv[n] = bias[co0 + wn * 32 + n * 16 + fr];
#pragma unroll
  for (int m = 0; m < 2; ++m)
#pragma unroll
    for (int r = 0; r < 4; ++r) {
      int x = wm * 32 + m * 16 + fc * 4 + r;
      size_t ra = (size_t)out_base + (size_t)y * out_row_stride + (size_t)x * 256 + co0 + wn * 32 + fr;
#pragma unroll
      for (int n = 0; n < 2; ++n) {
        float v = acc[m][n][r] + bv[n];
        ob[ra + n * 16] = __float2bfloat16(fmaxf(v, 0.f));
      }
    }
}

// ---------- 1x1 conv GEMM, 2-phase dbuf, BK=64, tile 64px x 64co ----------
template <bool KER>
__global__ __launch_bounds__(256) void conv1x1_mfma_k(
    const bf16_t* __restrict__ in, const bf16_t* __restrict__ wt,
    const float* __restrict__ bias, bf16_t* __restrict__ outw,
    float* __restrict__ outkb, int A0, int AS, long in_bstride, int comax) {
  __shared__ __align__(16) short ldsA[2][4096];
  __shared__ __align__(16) short ldsB[2][4096];
  const int t = threadIdx.x, w = t >> 6, lane = t & 63;
  const int y = blockIdx.x, co0 = blockIdx.y * 64, b = blockIdx.z;
  const bf16_t* inb = in + (size_t)b * in_bstride;
  const int wm = w >> 1, wn = w & 1;
  f32x4 acc[2][2] = {};

  int ar[2], ac[2];
#pragma unroll
  for (int p = 0; p < 2; ++p) {
    int u = (p * 4 + w) * 64 + lane;
    ar[p] = u >> 3;
    ac[p] = ((u & 7) ^ ((u >> 3) & 7)) * 8;
  }
  const int fr = lane & 15, fc = lane >> 4;

  auto stage = [&](int ks, int buf) {
    int cik = ks * 64;
#pragma unroll
    for (int p = 0; p < 2; ++p) {
      gload16(inb + (size_t)A0 + (size_t)y * AS + (size_t)ar[p] * 256 + cik + ac[p],
              &ldsA[buf][(p * 4 + w) * 512]);
      gload16(wt + (size_t)min(co0 + ar[p], comax - 1) * 256 + cik + ac[p],
              &ldsB[buf][(p * 4 + w) * 512]);
    }
  };
  auto compute = [&](int buf) {
#pragma unroll
    for (int kk = 0; kk < 2; ++kk) {
      bf16x8 af[2], bfr[2];
#pragma unroll
      for (int m = 0; m < 2; ++m) af[m] = swzread(ldsA[buf], wm * 32 + m * 16 + fr, kk * 4 + fc);
#pragma unroll
      for (int n = 0; n < 2; ++n) bfr[n] = swzread(ldsB[buf], wn * 32 + n * 16 + fr, kk * 4 + fc);
#pragma unroll
      for (int m = 0; m < 2; ++m)
#pragma unroll
        for (int n = 0; n < 2; ++n)
          acc[m][n] = __builtin_amdgcn_mfma_f32_16x16x32_bf16(af[m], bfr[n], acc[m][n], 0, 0, 0);
    }
  };

  stage(0, 0);
  __syncthreads();
  for (int ks = 0; ks < 3; ++ks) {
    stage(ks + 1, (ks + 1) & 1);
    compute(ks & 1);
    __syncthreads();
  }
  compute(1);

#pragma unroll
  for (int m = 0; m < 2; ++m)
#pragma unroll
    for (int r = 0; r < 4; ++r) {
      int x = wm * 32 + m * 16 + fc * 4 + r;
      int prow = y * 64 + x;
#pragma unroll
      for (int n = 0; n < 2; ++n) {
        int co = co0 + wn * 32 + n * 16 + fr;
        float v = acc[m][n][r] + bias[min(co, comax - 1)];
        if (KER) {
          if (co < 256) outw[((size_t)b * 4096 + prow) * 256 + co] = __float2bfloat16(v);
          else if (co == 256) outkb[(size_t)b * 4096 + prow] = v;
        } else {
          outw[((size_t)b * 4096 + prow) * 256 + co] = __float2bfloat16(v);
        }
      }
    }
}

// ---------- logits GEMM + mask + write + fused dice partials ----------
// grid (64 p-tiles, 32 q-tiles, B); tile 64p x 128q; BK=64, 4 steps, 2-phase
__global__ __launch_bounds__(256) void logits_mfma_k(
    const bf16_t* __restrict__ kwt, const float* __restrict__ kb,
    const bf16_t* __restrict__ fft, const float* __restrict__ masks,
    const int* __restrict__ layouts, float* __restrict__ out,
    float* __restrict__ partial) {
  __shared__ __align__(16) short ldsA[2][4096];
  __shared__ __align__(16) short ldsB[2][8192];
  const int t = threadIdx.x, w = t >> 6, lane = t & 63;
  const int p0 = blockIdx.x * 64, q0 = blockIdx.y * 128, b = blockIdx.z;
  const bf16_t* ab = kwt + (size_t)b * (4096 * 256);
  const bf16_t* bb = fft + (size_t)b * (4096 * 256);
  const int wm = w >> 1, wn = w & 1;
  f32x4 acc[2][4] = {};

  int ar[2], ac[2], br[4], bc[4];
#pragma unroll
  for (int p = 0; p < 2; ++p) {
    int u = (p * 4 + w) * 64 + lane;
    ar[p] = u >> 3;
    ac[p] = ((u & 7) ^ ((u >> 3) & 7)) * 8;
  }
#pragma unroll
  for (int p = 0; p < 4; ++p) {
    int u = (p * 4 + w) * 64 + lane;
    br[p] = u >> 3;
    bc[p] = ((u & 7) ^ ((u >> 3) & 7)) * 8;
  }
  const int fr = lane & 15, fc = lane >> 4;

  auto stage = [&](int ks, int buf) {
    int cik = ks * 64;
#pragma unroll
    for (int p = 0; p < 2; ++p)
      gload16(ab + (size_t)(p0 + ar[p]) * 256 + cik + ac[p], &ldsA[buf][(p * 4 + w) * 512]);
#pragma unroll
    for (int p = 0; p < 4; ++p)
      gload16(bb + (size_t)(q0 + br[p]) * 256 + cik + bc[p], &ldsB[buf][(p * 4 + w) * 512]);
  };
  auto compute = [&](int buf) {
#pragma unroll
    for (int kk = 0; kk < 2; ++kk) {
      bf16x8 af[2], bfr[4];
#pragma unroll
      for (int m = 0; m < 2; ++m) af[m] = swzread(ldsA[buf], wm * 32 + m * 16 + fr, kk * 4 + fc);
#pragma unroll
      for (int n = 0; n < 4; ++n) bfr[n] = swzread(ldsB[buf], wn * 64 + n * 16 + fr, kk * 4 + fc);
#pragma unroll
      for (int m = 0; m < 2; ++m)
#pragma unroll
        for (int n = 0; n < 4; ++n)
          acc[m][n] = __builtin_amdgcn_mfma_f32_16x16x32_bf16(af[m], bfr[n], acc[m][n], 0, 0, 0);
    }
  };

  stage(0, 0);
  __syncthreads();
  for (int ks = 0; ks < 3; ++ks) {
    stage(ks + 1, (ks + 1) & 1);
    compute(ks & 1);
    __syncthreads();
  }
  compute(1);

  float mq[4];
  int layq[4];
#pragma unroll
  for (int n = 0; n < 4; ++n) {
    int q = q0 + wn * 64 + n * 16 + fr;
    mq[n] = masks[b * 4096 + q];
    layq[n] = layouts[b * 4096 + q];
  }
  float sl[8];
#pragma unroll
  for (int i = 0; i < 8; ++i) sl[i] = 0.f;
  float* outb = out + (size_t)b * 4096 * 4096;
#pragma unroll
  for (int m = 0; m < 2; ++m) {
#pragma unroll
    for (int r = 0; r < 4; ++r) {
      int p = p0 + wm * 32 + m * 16 + fc * 4 + r;
      float kbv = kb[b * 4096 + p];
      int layp = layouts[b * 4096 + p];
      float s = 0.f;
      size_t ra = (size_t)p * 4096 + q0 + wn * 64 + fr;
#pragma unroll
      for (int n = 0; n < 4; ++n) {
        float lg = (mq[n] > 0.f) ? (acc[m][n][r] + kbv) : NEG_INF_V;
        outb[ra + n * 16] = lg;
        float pz = 1.f / (1.f + __expf(-lg));
        float lab = (layp == layq[n]) ? 1.f : 0.f;
        float d = 2.f * pz * lab / (pz * pz + lab + 0.002f);
        s += (1.f - d) * mq[n];
      }
      sl[m * 4 + r] = s;
    }
  }
#pragma unroll
  for (int i = 0; i < 8; ++i) {
    float v = sl[i];
    v += __shfl_xor(v, 1); v += __shfl_xor(v, 2);
    v += __shfl_xor(v, 4); v += __shfl_xor(v, 8);
    sl[i] = v;
  }
  if (fr == 0) {
    int qt = blockIdx.y * 2 + wn;
#pragma unroll
    for (int m = 0; m < 2; ++m)
#pragma unroll
      for (int r = 0; r < 4; ++r) {
        int p = p0 + wm * 32 + m * 16 + fc * 4 + r;
        partial[((size_t)b * 4096 + p) * 64 + qt] = sl[m * 4 + r];
      }
  }
}

// ---------- loss stage 1: per-p rowsum * mp, atomic accumulate ----------
__global__ __launch_bounds__(256) void rowsum_k(
    const float* __restrict__ partial, const float* __restrict__ masks,
    float* __restrict__ accum) {
  const int t = threadIdx.x, w = t >> 6, lane = t & 63;
  const int idx = blockIdx.x * 256 + t;
  const int b = idx >> 12;
  const float* pp = partial + (size_t)idx * 64;
  float s = 0.f;
#pragma unroll
  for (int k = 0; k < 64; ++k) s += pp[k];
  float mp = masks[idx];
  float num = s * mp;
#pragma unroll
  for (int off = 32; off; off >>= 1) {
    num += __shfl_down(num, off);
    mp += __shfl_down(mp, off);
  }
  __shared__ float sn[4], sm[4];
  if (lane == 0) { sn[w] = num; sm[w] = mp; }
  __syncthreads();
  if (t == 0) {
    atomicAdd(&accum[b * 2], sn[0] + sn[1] + sn[2] + sn[3]);
    atomicAdd(&accum[b * 2 + 1], sm[0] + sm[1] + sm[2] + sm[3]);
  }
}

__global__ void loss_final_k(const float* __restrict__ accum, float* __restrict__ out_loss) {
  if (threadIdx.x == 0) {
    float l0 = accum[0] / (accum[1] * accum[1] + 1e-5f);
    float l1 = accum[2] / (accum[3] * accum[3] + 1e-5f);
    out_loss[0] = 0.5f * (l0 + l1);
  }
}

extern "C" void kernel_launch(void* const* d_in, const int* in_sizes, int n_in,
                              void* d_out, int out_size, void* d_ws, size_t ws_size,
                              hipStream_t stream) {
  const float* feats = (const float*)d_in[0];
  const float* masks = (const float*)d_in[1];
  const int* layouts = (const int*)d_in[2];
  const float* w_pre0 = (const float*)d_in[3];
  const float* b_pre0 = (const float*)d_in[4];
  const float* w_pre1 = (const float*)d_in[5];
  const float* b_pre1 = (const float*)d_in[6];
  const float* w_kernel = (const float*)d_in[7];
  const float* b_kernel = (const float*)d_in[8];
  const float* w_feats = (const float*)d_in[9];
  const float* b_feats = (const float*)d_in[10];

  bf16_t* x_pad = (bf16_t*)d_ws;                 // 2*1115136
  bf16_t* h1p = x_pad + 2 * 1115136;             // 2*1115136
  bf16_t* h2 = h1p + 2 * 1115136;                // 2*1048576
  bf16_t* w0r = h2 + 2 * 1048576;                // 589824
  bf16_t* w1r = w0r + 589824;                    // 589824
  bf16_t* wkb = w1r + 589824;                    // 65792
  bf16_t* wfb = wkb + 65792;                     // 65536
  bf16_t* kwt = wfb + 65536;                     // 2*1048576
  bf16_t* fft = kwt + 2 * 1048576;               // 2*1048576
  float* kb = (float*)(fft + 2 * 1048576);       // 8192
  float* partial = kb + 8192;                    // 524288
  float* accum = partial + 524288;               // 4
  float* out = (float*)d_out;

  hipMemsetAsync(x_pad, 0, (size_t)4 * 1115136 * sizeof(bf16_t), stream);
  hipMemsetAsync(accum, 0, 4 * sizeof(float), stream);

  pad_cast_k<<<dim3(64, 4, 2), 256, 0, stream>>>(feats, x_pad);
  castw3_k<<<dim3(256, 2), 256, 0, stream>>>(w_pre0, w_pre1, w0r, w1r);
  castw1_k<<<dim3(514), 256, 0, stream>>>(w_kernel, w_feats, wkb, wfb);

  conv3x3_mfma_k<<<dim3(64, 4, 2), 256, 0, stream>>>(
      x_pad, w0r, b_pre0, h1p, 66 * 256, 67 * 256, 1115136L);
  conv3x3_mfma_k<<<dim3(64, 4, 2), 256, 0, stream>>>(
      h1p, w1r, b_pre1, h2, 64 * 256, 0, 1048576L);

  conv1x1_mfma_k<true><<<dim3(64, 5, 2), 256, 0, stream>>>(
      h2, wkb, b_kernel, kwt, kb, 0, 16384, 1048576L, 257);
  conv1x1_mfma_k<false><<<dim3(64, 4, 2), 256, 0, stream>>>(
      x_pad, wfb, b_feats, fft, nullptr, 67 * 256, 66 * 256, 1115136L, 256);

  logits_mfma_k<<<dim3(64, 32, 2), 256, 0, stream>>>(
      kwt, kb, fft, masks, layouts, out, partial);

  rowsum_k<<<dim3(32), 256, 0, stream>>>(partial, masks, accum);
  loss_final_k<<<1, 64, 0, stream>>>(accum, out + (size_t)2 * 4096 * 4096);
}